// Round 1
// baseline (2646.898 us; speedup 1.0000x reference)
//
#include <hip/hip_runtime.h>
#include <cmath>

#define BATCH 64
#define SEQL  32
#define EMBD  300
#define HIDD  500
#define G4    2000
#define NOBJ  64
#define GHID  100
#define ANSN  1000

__device__ __forceinline__ float sigmf(float x){ return 1.f/(1.f+expf(-x)); }

// ---------------- embedding gather: emb[r][k] = table[sent[r]][k] ----------------
__global__ void k_emb(const int* __restrict__ sent, const float* __restrict__ table,
                      float* __restrict__ emb)
{
    int idx = blockIdx.x*blockDim.x + threadIdx.x;
    if (idx < BATCH*SEQL*EMBD){
        int r = idx / EMBD;
        int k = idx - r*EMBD;
        emb[idx] = table[sent[r]*EMBD + k];
    }
}

// ---------------- generic tiled f32 GEMM: C = A(MxK) @ Bw(NxK)^T + bias ----------------
#define GBM 64
#define GBN 64
#define GBK 16
__global__ __launch_bounds__(256) void k_gemm_bt(const float* __restrict__ A, const float* __restrict__ Bw,
                 const float* __restrict__ bias0, const float* __restrict__ bias1,
                 float* __restrict__ Co, int M, int N, int K)
{
    __shared__ float As[GBK][GBM+1];
    __shared__ float Bs[GBK][GBN+1];
    int bm = blockIdx.y*GBM, bn = blockIdx.x*GBN;
    int tid = threadIdx.x;
    int tx = tid & 15, ty = tid >> 4;
    float acc[4][4] = {};
    for (int k0 = 0; k0 < K; k0 += GBK){
        for (int i = tid; i < GBM*GBK; i += 256){
            int m = i >> 4, k = i & 15;
            int gm = bm+m, gk = k0+k;
            As[k][m] = (gm < M && gk < K) ? A[(size_t)gm*K+gk] : 0.f;
        }
        for (int i = tid; i < GBN*GBK; i += 256){
            int n = i >> 4, k = i & 15;
            int gn = bn+n, gk = k0+k;
            Bs[k][n] = (gn < N && gk < K) ? Bw[(size_t)gn*K+gk] : 0.f;
        }
        __syncthreads();
        #pragma unroll
        for (int kk = 0; kk < GBK; ++kk){
            float a[4], b[4];
            #pragma unroll
            for (int i=0;i<4;i++) a[i] = As[kk][ty*4+i];
            #pragma unroll
            for (int j=0;j<4;j++) b[j] = Bs[kk][tx*4+j];
            #pragma unroll
            for (int i=0;i<4;i++)
                #pragma unroll
                for (int j=0;j<4;j++) acc[i][j] += a[i]*b[j];
        }
        __syncthreads();
    }
    #pragma unroll
    for (int i=0;i<4;i++){
        int gm = bm + ty*4 + i; if (gm >= M) continue;
        #pragma unroll
        for (int j=0;j<4;j++){
            int gn = bn + tx*4 + j; if (gn >= N) continue;
            float v = acc[i][j];
            if (bias0) v += bias0[gn];
            if (bias1) v += bias1[gn];
            Co[(size_t)gm*N+gn] = v;
        }
    }
}

// ---------------- one LSTM step: gates = h@Whh^T + xg[:,t,:]; pointwise; mask ----------------
// block = 8 hidden units (all 4 gates, all 64 batch rows). grid = 63.
#define LBK 25
__global__ __launch_bounds__(256) void k_lstm_step(const float* __restrict__ hin, float* __restrict__ hout,
                   float* __restrict__ cst, const float* __restrict__ xg,
                   const float* __restrict__ Whh, const int* __restrict__ lens, int t)
{
    __shared__ float As[LBK][BATCH+1];
    __shared__ float Bs[LBK][33];
    __shared__ float gl[BATCH][33];
    int u0 = blockIdx.x * 8;
    int tid = threadIdx.x;
    int tx = tid & 15, ty = tid >> 4;
    float acc[4][2] = {};
    for (int k0 = 0; k0 < HIDD; k0 += LBK){
        for (int i = tid; i < BATCH*LBK; i += 256){
            int bb = i / LBK, k = i % LBK;
            As[k][bb] = hin[bb*HIDD + k0 + k];
        }
        for (int i = tid; i < 32*LBK; i += 256){
            int cc = i / LBK, k = i % LBK;
            int u = u0 + (cc & 7);
            int jrow = (cc >> 3)*HIDD + u;
            Bs[k][cc] = (u < HIDD) ? Whh[(size_t)jrow*HIDD + k0 + k] : 0.f;
        }
        __syncthreads();
        #pragma unroll
        for (int kk = 0; kk < LBK; ++kk){
            float a0 = As[kk][ty*4+0], a1 = As[kk][ty*4+1];
            float a2 = As[kk][ty*4+2], a3 = As[kk][ty*4+3];
            float b0 = Bs[kk][tx*2+0], b1 = Bs[kk][tx*2+1];
            acc[0][0]+=a0*b0; acc[0][1]+=a0*b1;
            acc[1][0]+=a1*b0; acc[1][1]+=a1*b1;
            acc[2][0]+=a2*b0; acc[2][1]+=a2*b1;
            acc[3][0]+=a3*b0; acc[3][1]+=a3*b1;
        }
        __syncthreads();
    }
    #pragma unroll
    for (int i=0;i<4;i++){
        #pragma unroll
        for (int jj=0;jj<2;jj++){
            int bb = ty*4+i, cc = tx*2+jj;
            int u = u0 + (cc & 7), g = cc >> 3;
            if (u < HIDD)
                gl[bb][cc] = acc[i][jj] + xg[((size_t)bb*SEQL + t)*G4 + g*HIDD + u];
        }
    }
    __syncthreads();
    for (int it = tid; it < BATCH*8; it += 256){
        int bb = it >> 3, uu = it & 7;
        int u = u0 + uu;
        if (u >= HIDD) continue;
        float gi = gl[bb][uu], gf = gl[bb][8+uu], gg = gl[bb][16+uu], go = gl[bb][24+uu];
        float si = sigmf(gi), sf = sigmf(gf), so = sigmf(go);
        float tg = tanhf(gg);
        float cold = cst[bb*HIDD+u];
        float cn = sf*cold + si*tg;
        float hn = so*tanhf(cn);
        bool m = (t < lens[bb]);
        hout[bb*HIDD+u] = m ? hn : hin[bb*HIDD+u];
        if (m) cst[bb*HIDD+u] = cn;
    }
}

// ---------------- q_part: qp[b][n] = q[b]·g1_w[n][0:500] + g1_b[n] ----------------
__global__ void k_qp(const float* __restrict__ q, const float* __restrict__ g1w,
                     const float* __restrict__ g1b, float* __restrict__ qp)
{
    int idx = blockIdx.x*blockDim.x + threadIdx.x;
    if (idx >= BATCH*GHID) return;
    int b = idx / GHID, n = idx % GHID;
    const float* qa = q + b*HIDD;
    const float* wr = g1w + n*548;
    float s = g1b[n];
    for (int k = 0; k < HIDD; ++k) s += qa[k]*wr[k];
    qp[idx] = s;
}

// ---------------- i_part/j_part: dot over C=24 of obj (transposed conv) ----------------
__global__ void k_ipjp(const float* __restrict__ conv, const float* __restrict__ g1w,
                       float* __restrict__ ip, float* __restrict__ jp)
{
    int idx = blockIdx.x*blockDim.x + threadIdx.x;
    if (idx >= BATCH*NOBJ*GHID) return;
    int b = idx / (NOBJ*GHID);
    int rem = idx - b*(NOBJ*GHID);
    int o = rem / GHID, n = rem % GHID;
    const float* wj = g1w + n*548 + 500;   // conv_expand_1 (j) block
    const float* wi = g1w + n*548 + 524;   // conv_expand_2 (i) block
    float si = 0.f, sj = 0.f;
    #pragma unroll
    for (int c = 0; c < 24; ++c){
        float v = conv[((size_t)b*24 + c)*NOBJ + o];
        sj += v*wj[c];
        si += v*wi[c];
    }
    ip[idx] = si;
    jp[idx] = sj;
}

// ---------------- fused pair kernel: h1 on the fly, g2 GEMM, partial sum ----------------
// block = (b, 4 i's x all 64 j's) = 256 pairs.  grid = 64*16.
__global__ __launch_bounds__(256) void k_pair(const float* __restrict__ qp, const float* __restrict__ ip,
              const float* __restrict__ jp, const float* __restrict__ g2w,
              const float* __restrict__ g2b, float* __restrict__ part)
{
    __shared__ float jpl[NOBJ][GHID+1];
    __shared__ float basel[4][GHID];
    __shared__ float g2wl[GHID*GHID];
    int b  = blockIdx.x >> 4;
    int ic = blockIdx.x & 15;
    int tid = threadIdx.x;
    for (int i = tid; i < NOBJ*GHID; i += 256){
        int j = i / GHID, k = i % GHID;
        jpl[j][k] = jp[((size_t)b*NOBJ + j)*GHID + k];
    }
    for (int i = tid; i < 4*GHID; i += 256){
        int ii = i / GHID, k = i % GHID;
        basel[ii][k] = qp[b*GHID + k] + ip[((size_t)b*NOBJ + ic*4 + ii)*GHID + k];
    }
    for (int i = tid; i < GHID*GHID; i += 256) g2wl[i] = g2w[i];
    __syncthreads();

    int j  = tid & 63;   // lane = pair column j
    int nt = tid >> 6;   // 0..3 -> 25 outputs each
    float acc[4][25] = {};
    for (int k = 0; k < GHID; ++k){
        float jv = jpl[j][k];
        float a0 = fmaxf(basel[0][k] + jv, 0.f);
        float a1 = fmaxf(basel[1][k] + jv, 0.f);
        float a2 = fmaxf(basel[2][k] + jv, 0.f);
        float a3 = fmaxf(basel[3][k] + jv, 0.f);
        #pragma unroll
        for (int nn = 0; nn < 25; ++nn){
            float w = g2wl[(nt*25+nn)*GHID + k];   // broadcast across lanes
            acc[0][nn] += a0*w;
            acc[1][nn] += a1*w;
            acc[2][nn] += a2*w;
            acc[3][nn] += a3*w;
        }
    }
    // epilogue: h2 = relu(acc + g2b); reduce over the block's 256 pairs
    #pragma unroll
    for (int nn = 0; nn < 25; ++nn){
        int n = nt*25 + nn;
        float gb = g2b[n];
        float s = fmaxf(acc[0][nn]+gb, 0.f) + fmaxf(acc[1][nn]+gb, 0.f)
                + fmaxf(acc[2][nn]+gb, 0.f) + fmaxf(acc[3][nn]+gb, 0.f);
        #pragma unroll
        for (int off = 32; off > 0; off >>= 1) s += __shfl_down(s, off);
        if ((tid & 63) == 0) part[(size_t)blockIdx.x*GHID + n] = s;
    }
}

// ---------------- final: reduce partials, f1, f2, log_softmax ----------------
__global__ __launch_bounds__(256) void k_final(const float* __restrict__ part, const float* __restrict__ f1w,
               const float* __restrict__ f1b, const float* __restrict__ f2w,
               const float* __restrict__ f2b, float* __restrict__ out)
{
    int b = blockIdx.x;
    int tid = threadIdx.x;
    __shared__ float gs[GHID];
    __shared__ float fh[GHID];
    __shared__ float lg[ANSN];
    __shared__ float red[4], red2[4];
    if (tid < GHID){
        float s = 0.f;
        for (int ic = 0; ic < 16; ++ic) s += part[((size_t)b*16 + ic)*GHID + tid];
        gs[tid] = s;
    }
    __syncthreads();
    if (tid < GHID){
        float s = f1b[tid];
        const float* w = f1w + tid*GHID;
        for (int k = 0; k < GHID; ++k) s += gs[k]*w[k];
        fh[tid] = fmaxf(s, 0.f);
    }
    __syncthreads();
    for (int n = tid; n < ANSN; n += 256){
        float s = f2b[n];
        const float* w = f2w + (size_t)n*GHID;
        for (int k = 0; k < GHID; ++k) s += fh[k]*w[k];
        lg[n] = fmaxf(s, 0.f);
    }
    __syncthreads();
    float mx = -1e30f;
    for (int n = tid; n < ANSN; n += 256) mx = fmaxf(mx, lg[n]);
    #pragma unroll
    for (int off = 32; off > 0; off >>= 1) mx = fmaxf(mx, __shfl_xor(mx, off));
    if ((tid & 63) == 0) red[tid >> 6] = mx;
    __syncthreads();
    mx = fmaxf(fmaxf(red[0], red[1]), fmaxf(red[2], red[3]));
    float se = 0.f;
    for (int n = tid; n < ANSN; n += 256) se += expf(lg[n]-mx);
    #pragma unroll
    for (int off = 32; off > 0; off >>= 1) se += __shfl_xor(se, off);
    if ((tid & 63) == 0) red2[tid >> 6] = se;
    __syncthreads();
    se = red2[0]+red2[1]+red2[2]+red2[3];
    float lse = logf(se);
    for (int n = tid; n < ANSN; n += 256) out[(size_t)b*ANSN + n] = lg[n] - mx - lse;
}

extern "C" void kernel_launch(void* const* d_in, const int* in_sizes, int n_in,
                              void* d_out, int out_size, void* d_ws, size_t ws_size,
                              hipStream_t stream)
{
    const int*   sent  = (const int*)  d_in[0];
    const float* conv  = (const float*)d_in[1];
    const int*   lens  = (const int*)  d_in[2];
    const float* table = (const float*)d_in[3];
    const float* W_ih  = (const float*)d_in[4];
    const float* W_hh  = (const float*)d_in[5];
    const float* b_ih  = (const float*)d_in[6];
    const float* b_hh  = (const float*)d_in[7];
    const float* h0    = (const float*)d_in[8];
    const float* c0    = (const float*)d_in[9];
    const float* g1_w  = (const float*)d_in[10];
    const float* g1_b  = (const float*)d_in[11];
    const float* g2_w  = (const float*)d_in[12];
    const float* g2_b  = (const float*)d_in[13];
    const float* f1_w  = (const float*)d_in[14];
    const float* f1_b  = (const float*)d_in[15];
    const float* f2_w  = (const float*)d_in[16];
    const float* f2_b  = (const float*)d_in[17];
    float* out = (float*)d_out;

    float* ws   = (float*)d_ws;
    float* emb  = ws;                           // 2048*300
    float* xg   = emb + BATCH*SEQL*EMBD;        // 2048*2000
    float* hb0  = xg  + (size_t)BATCH*SEQL*G4;  // 64*500
    float* hb1  = hb0 + BATCH*HIDD;
    float* cws  = hb1 + BATCH*HIDD;
    float* qp   = cws + BATCH*HIDD;             // 64*100
    float* ip   = qp  + BATCH*GHID;             // 64*64*100
    float* jp   = ip  + BATCH*NOBJ*GHID;
    float* part = jp  + BATCH*NOBJ*GHID;        // 1024*100

    // 1. embedding gather
    k_emb<<<(BATCH*SEQL*EMBD + 255)/256, 256, 0, stream>>>(sent, table, emb);

    // 2. X-gates for all timesteps: xg = emb @ W_ih^T + (b_ih+b_hh)
    {
        dim3 g((G4 + GBN - 1)/GBN, (BATCH*SEQL + GBM - 1)/GBM);
        k_gemm_bt<<<g, 256, 0, stream>>>(emb, W_ih, b_ih, b_hh, xg,
                                          BATCH*SEQL, G4, EMBD);
    }

    // 3. LSTM init + 32 sequential steps (double-buffered h, in-place c)
    hipMemcpyAsync(hb0, h0, BATCH*HIDD*sizeof(float), hipMemcpyDeviceToDevice, stream);
    hipMemcpyAsync(cws, c0, BATCH*HIDD*sizeof(float), hipMemcpyDeviceToDevice, stream);
    for (int t = 0; t < SEQL; ++t){
        const float* hi = (t & 1) ? hb1 : hb0;
        float*       ho = (t & 1) ? hb0 : hb1;
        k_lstm_step<<<(HIDD + 7)/8, 256, 0, stream>>>(hi, ho, cws, xg, W_hh, lens, t);
    }
    const float* q = hb0;  // SEQL even -> final h lands in hb0

    // 4. g_mlp layer-1 partials
    k_qp<<<(BATCH*GHID + 255)/256, 256, 0, stream>>>(q, g1_w, g1_b, qp);
    k_ipjp<<<(BATCH*NOBJ*GHID + 255)/256, 256, 0, stream>>>(conv, g1_w, ip, jp);

    // 5. fused pair kernel -> per-block partial sums
    k_pair<<<BATCH*16, 256, 0, stream>>>(qp, ip, jp, g2_w, g2_b, part);

    // 6. final MLP + log_softmax
    k_final<<<BATCH, 256, 0, stream>>>(part, f1_w, f1_b, f2_w, f2_b, out);
}

// Round 2
// 1400.578 us; speedup vs baseline: 1.8899x; 1.8899x over previous
//
#include <hip/hip_runtime.h>
#include <hip/hip_cooperative_groups.h>
#include <cmath>

#define BATCH 64
#define SEQL  32
#define EMBD  300
#define HIDD  500
#define NOBJ  64
#define GHID  100
#define ANSN  1000
#define MCOL  2048   // t*64+b column dimension

namespace cg = cooperative_groups;

__device__ __forceinline__ float sigmf(float x){ return 1.f/(1.f+expf(-x)); }

// ---------------- embT[k][t*64+b] = table[sent[b*32+t]][k] ----------------
// grid: (3 ktiles of 100, 32 t)
__global__ void k_embT(const int* __restrict__ sent, const float* __restrict__ table,
                       float* __restrict__ embT)
{
    __shared__ float T[64][101];
    int t  = blockIdx.y;
    int k0 = blockIdx.x * 100;
    int tid = threadIdx.x;
    for (int i = tid; i < 64*100; i += 256){
        int b = i / 100, k = i - b*100;
        T[b][k] = table[(size_t)sent[b*SEQL + t]*EMBD + k0 + k];
    }
    __syncthreads();
    for (int i = tid; i < 100*64; i += 256){
        int k = i >> 6, b = i & 63;
        embT[(size_t)(k0+k)*MCOL + t*64 + b] = T[b][k];
    }
}

// ---------------- NN GEMM: C[n][m] = sum_k A[n][k]*B[k][m] + bias0[n]+bias1[n] ----------------
__global__ __launch_bounds__(256) void k_gemm_nn(const float* __restrict__ A, const float* __restrict__ B,
                 const float* __restrict__ bias0, const float* __restrict__ bias1,
                 float* __restrict__ C, int N, int M, int K)
{
    __shared__ float As[16][65];
    __shared__ float Bs[16][65];
    int n0 = blockIdx.y*64, m0 = blockIdx.x*64;
    int tid = threadIdx.x, tx = tid & 15, ty = tid >> 4;
    float acc[4][4] = {};
    for (int k0 = 0; k0 < K; k0 += 16){
        for (int i = tid; i < 64*16; i += 256){
            int n = i >> 4, k = i & 15;
            As[k][n] = (n0+n < N && k0+k < K) ? A[(size_t)(n0+n)*K + k0+k] : 0.f;
        }
        for (int i = tid; i < 16*64; i += 256){
            int k = i >> 6, m = i & 63;
            Bs[k][m] = (k0+k < K) ? B[(size_t)(k0+k)*M + m0+m] : 0.f;
        }
        __syncthreads();
        #pragma unroll
        for (int kk = 0; kk < 16; ++kk){
            float a[4], b[4];
            #pragma unroll
            for (int i=0;i<4;i++) a[i] = As[kk][ty*4+i];
            #pragma unroll
            for (int j=0;j<4;j++) b[j] = Bs[kk][tx*4+j];
            #pragma unroll
            for (int i=0;i<4;i++)
                #pragma unroll
                for (int j=0;j<4;j++) acc[i][j] += a[i]*b[j];
        }
        __syncthreads();
    }
    #pragma unroll
    for (int i=0;i<4;i++){
        int n = n0 + ty*4 + i;
        if (n >= N) continue;
        float bsum = bias0[n] + bias1[n];
        float4 v;
        v.x = acc[i][0]+bsum; v.y = acc[i][1]+bsum; v.z = acc[i][2]+bsum; v.w = acc[i][3]+bsum;
        *(float4*)(C + (size_t)n*M + m0 + tx*4) = v;
    }
}

// ---------------- persistent cooperative LSTM: all 32 steps in one kernel ----------------
// grid = 250 blocks, block owns units u0=2*bid, u0+1 (8 gate rows).
// h kept transposed in ws: hT[512][64] (rows 500..511 zero pad).
// wave w stages k-quarter [128w,128w+128) of hT into its LDS region, computes all 8 rows
// over that quarter with scalar-loaded (wave-uniform) W_hh float4s, then cross-wave reduce.
__global__ __launch_bounds__(256, 1) void k_lstm_all(float* __restrict__ hT,
    const float* __restrict__ xgT, const float* __restrict__ Whh,
    const float* __restrict__ h0, const float* __restrict__ c0,
    const int* __restrict__ lens)
{
    __shared__ float hs[4][8192];          // 128 KB: [wave][k_local*64 + b]
    float* gl = &hs[0][0];                 // overlay: 4*8*64 floats, used after all hs reads

    int tid  = threadIdx.x;
    int bid  = blockIdx.x;
    int u0   = bid * 2;
    int w    = __builtin_amdgcn_readfirstlane(tid >> 6);
    int lane = tid & 63;

    // persistent per-thread state for pointwise (threads 0..127): (uu = tid>>6, b = lane)
    float cprev = 0.f, hprev = 0.f; int mylen = 0;
    if (tid < 128){
        int b = lane, uu = tid >> 6;
        cprev = c0[b*HIDD + u0 + uu];
        hprev = h0[b*HIDD + u0 + uu];
        mylen = lens[b];
        hT[(u0+uu)*64 + b] = hprev;
    }
    if (bid == 0){
        for (int i = tid; i < 12*64; i += 256) hT[HIDD*64 + i] = 0.f;  // zero pad rows 500..511
    }
    cg::this_grid().sync();

    const int    kq0    = w * 128;
    const size_t hquart = (size_t)kq0 * 64;

    for (int t = 0; t < SEQL; ++t){
        // stage this wave's k-quarter of hT into hs[w] (each wave reads only its own region)
        {
            const float4* src = (const float4*)(hT + hquart);
            float4* dst = (float4*)(&hs[w][0]);
            #pragma unroll
            for (int i = 0; i < 32; ++i)
                dst[i*64 + lane] = src[i*64 + lane];
        }
        float acc[8] = {0,0,0,0,0,0,0,0};
        #pragma unroll 4
        for (int k4 = 0; k4 < 128; k4 += 4){
            int kk = kq0 + k4;
            if (kk < HIDD){                      // wave-uniform branch (pad tail skip)
                float a0 = hs[w][(k4+0)*64 + lane];
                float a1 = hs[w][(k4+1)*64 + lane];
                float a2 = hs[w][(k4+2)*64 + lane];
                float a3 = hs[w][(k4+3)*64 + lane];
                #pragma unroll
                for (int r = 0; r < 8; ++r){
                    int row = (r>>1)*HIDD + u0 + (r&1);   // gate g=r>>1, unit uu=r&1
                    float4 wv = *(const float4*)(Whh + (size_t)row*HIDD + kk);  // uniform -> s_load
                    acc[r] += a0*wv.x + a1*wv.y + a2*wv.z + a3*wv.w;
                }
            }
        }
        __syncthreads();                        // all waves done reading hs before gl overlay
        #pragma unroll
        for (int r = 0; r < 8; ++r) gl[(w*8 + r)*64 + lane] = acc[r];
        __syncthreads();
        if (tid < 128){
            int b = lane, uu = tid >> 6;
            float g4[4];
            #pragma unroll
            for (int g = 0; g < 4; ++g){
                int r = g*2 + uu;
                float s = gl[r*64+b] + gl[(8+r)*64+b] + gl[(16+r)*64+b] + gl[(24+r)*64+b];
                s += xgT[(size_t)(g*HIDD + u0 + uu)*MCOL + t*64 + b];
                g4[g] = s;
            }
            float si = sigmf(g4[0]);
            float sf = sigmf(g4[1]);
            float tg = tanhf(g4[2]);
            float so = sigmf(g4[3]);
            float cn = sf*cprev + si*tg;
            float hn = so*tanhf(cn);
            if (t < mylen){ cprev = cn; hprev = hn; }
            hT[(u0+uu)*64 + b] = hprev;
        }
        cg::this_grid().sync();
    }
}

// ---------------- q_part from transposed q: qp[b][n] = sum_k qT[k][b]*g1w[n][k] + g1b[n] ----------------
__global__ void k_qp(const float* __restrict__ qT, const float* __restrict__ g1w,
                     const float* __restrict__ g1b, float* __restrict__ qp)
{
    int idx = blockIdx.x*blockDim.x + threadIdx.x;
    if (idx >= BATCH*GHID) return;
    int b = idx / GHID, n = idx % GHID;
    const float* wr = g1w + n*548;
    float s = g1b[n];
    for (int k = 0; k < HIDD; ++k) s += qT[k*64 + b]*wr[k];
    qp[idx] = s;
}

// ---------------- i_part/j_part: dot over C=24 of obj (transposed conv) ----------------
__global__ void k_ipjp(const float* __restrict__ conv, const float* __restrict__ g1w,
                       float* __restrict__ ip, float* __restrict__ jp)
{
    int idx = blockIdx.x*blockDim.x + threadIdx.x;
    if (idx >= BATCH*NOBJ*GHID) return;
    int b = idx / (NOBJ*GHID);
    int rem = idx - b*(NOBJ*GHID);
    int o = rem / GHID, n = rem % GHID;
    const float* wj = g1w + n*548 + 500;   // conv_expand_1 (j) block
    const float* wi = g1w + n*548 + 524;   // conv_expand_2 (i) block
    float si = 0.f, sj = 0.f;
    #pragma unroll
    for (int c = 0; c < 24; ++c){
        float v = conv[((size_t)b*24 + c)*NOBJ + o];
        sj += v*wj[c];
        si += v*wi[c];
    }
    ip[idx] = si;
    jp[idx] = sj;
}

// ---------------- fused pair kernel: h1 on the fly, g2 GEMM, partial sum ----------------
__global__ __launch_bounds__(256) void k_pair(const float* __restrict__ qp, const float* __restrict__ ip,
              const float* __restrict__ jp, const float* __restrict__ g2w,
              const float* __restrict__ g2b, float* __restrict__ part)
{
    __shared__ float jpl[NOBJ][GHID+1];
    __shared__ float basel[4][GHID];
    __shared__ float g2wl[GHID*GHID];
    int b  = blockIdx.x >> 4;
    int ic = blockIdx.x & 15;
    int tid = threadIdx.x;
    for (int i = tid; i < NOBJ*GHID; i += 256){
        int j = i / GHID, k = i % GHID;
        jpl[j][k] = jp[((size_t)b*NOBJ + j)*GHID + k];
    }
    for (int i = tid; i < 4*GHID; i += 256){
        int ii = i / GHID, k = i % GHID;
        basel[ii][k] = qp[b*GHID + k] + ip[((size_t)b*NOBJ + ic*4 + ii)*GHID + k];
    }
    for (int i = tid; i < GHID*GHID; i += 256) g2wl[i] = g2w[i];
    __syncthreads();

    int j  = tid & 63;
    int nt = tid >> 6;
    float acc[4][25] = {};
    for (int k = 0; k < GHID; ++k){
        float jv = jpl[j][k];
        float a0 = fmaxf(basel[0][k] + jv, 0.f);
        float a1 = fmaxf(basel[1][k] + jv, 0.f);
        float a2 = fmaxf(basel[2][k] + jv, 0.f);
        float a3 = fmaxf(basel[3][k] + jv, 0.f);
        #pragma unroll
        for (int nn = 0; nn < 25; ++nn){
            float w = g2wl[(nt*25+nn)*GHID + k];
            acc[0][nn] += a0*w;
            acc[1][nn] += a1*w;
            acc[2][nn] += a2*w;
            acc[3][nn] += a3*w;
        }
    }
    #pragma unroll
    for (int nn = 0; nn < 25; ++nn){
        int n = nt*25 + nn;
        float gb = g2b[n];
        float s = fmaxf(acc[0][nn]+gb, 0.f) + fmaxf(acc[1][nn]+gb, 0.f)
                + fmaxf(acc[2][nn]+gb, 0.f) + fmaxf(acc[3][nn]+gb, 0.f);
        #pragma unroll
        for (int off = 32; off > 0; off >>= 1) s += __shfl_down(s, off);
        if ((tid & 63) == 0) part[(size_t)blockIdx.x*GHID + n] = s;
    }
}

// ---------------- final: reduce partials, f1, f2, log_softmax ----------------
__global__ __launch_bounds__(256) void k_final(const float* __restrict__ part, const float* __restrict__ f1w,
               const float* __restrict__ f1b, const float* __restrict__ f2w,
               const float* __restrict__ f2b, float* __restrict__ out)
{
    int b = blockIdx.x;
    int tid = threadIdx.x;
    __shared__ float gs[GHID];
    __shared__ float fh[GHID];
    __shared__ float lg[ANSN];
    __shared__ float red[4], red2[4];
    if (tid < GHID){
        float s = 0.f;
        for (int ic = 0; ic < 16; ++ic) s += part[((size_t)b*16 + ic)*GHID + tid];
        gs[tid] = s;
    }
    __syncthreads();
    if (tid < GHID){
        float s = f1b[tid];
        const float* w = f1w + tid*GHID;
        for (int k = 0; k < GHID; ++k) s += gs[k]*w[k];
        fh[tid] = fmaxf(s, 0.f);
    }
    __syncthreads();
    for (int n = tid; n < ANSN; n += 256){
        float s = f2b[n];
        const float* w = f2w + (size_t)n*GHID;
        for (int k = 0; k < GHID; ++k) s += fh[k]*w[k];
        lg[n] = fmaxf(s, 0.f);
    }
    __syncthreads();
    float mx = -1e30f;
    for (int n = tid; n < ANSN; n += 256) mx = fmaxf(mx, lg[n]);
    #pragma unroll
    for (int off = 32; off > 0; off >>= 1) mx = fmaxf(mx, __shfl_xor(mx, off));
    if ((tid & 63) == 0) red[tid >> 6] = mx;
    __syncthreads();
    mx = fmaxf(fmaxf(red[0], red[1]), fmaxf(red[2], red[3]));
    float se = 0.f;
    for (int n = tid; n < ANSN; n += 256) se += expf(lg[n]-mx);
    #pragma unroll
    for (int off = 32; off > 0; off >>= 1) se += __shfl_xor(se, off);
    if ((tid & 63) == 0) red2[tid >> 6] = se;
    __syncthreads();
    se = red2[0]+red2[1]+red2[2]+red2[3];
    float lse = logf(se);
    for (int n = tid; n < ANSN; n += 256) out[(size_t)b*ANSN + n] = lg[n] - mx - lse;
}

extern "C" void kernel_launch(void* const* d_in, const int* in_sizes, int n_in,
                              void* d_out, int out_size, void* d_ws, size_t ws_size,
                              hipStream_t stream)
{
    const int*   sent  = (const int*)  d_in[0];
    const float* conv  = (const float*)d_in[1];
    const int*   lens  = (const int*)  d_in[2];
    const float* table = (const float*)d_in[3];
    const float* W_ih  = (const float*)d_in[4];
    const float* W_hh  = (const float*)d_in[5];
    const float* b_ih  = (const float*)d_in[6];
    const float* b_hh  = (const float*)d_in[7];
    const float* h0    = (const float*)d_in[8];
    const float* c0    = (const float*)d_in[9];
    const float* g1_w  = (const float*)d_in[10];
    const float* g1_b  = (const float*)d_in[11];
    const float* g2_w  = (const float*)d_in[12];
    const float* g2_b  = (const float*)d_in[13];
    const float* f1_w  = (const float*)d_in[14];
    const float* f1_b  = (const float*)d_in[15];
    const float* f2_w  = (const float*)d_in[16];
    const float* f2_b  = (const float*)d_in[17];
    float* out = (float*)d_out;

    float* ws   = (float*)d_ws;
    float* embT = ws;                                  // 300*2048   = 614400
    float* xgT  = embT + (size_t)EMBD*MCOL;            // 2000*2048  = 4096000
    float* hT   = xgT  + (size_t)4*HIDD*MCOL;          // 512*64     = 32768
    float* qp   = hT   + 512*64;                       // 64*100
    float* ip   = qp   + BATCH*GHID;                   // 64*64*100
    float* jp   = ip   + BATCH*NOBJ*GHID;
    float* part = jp   + BATCH*NOBJ*GHID;              // 1024*100

    // 1. embedding gather, transposed to [k][t*64+b]
    {
        dim3 g(3, SEQL);
        k_embT<<<g, 256, 0, stream>>>(sent, table, embT);
    }

    // 2. xgT[row][t*64+b] = W_ih @ embT + (b_ih+b_hh)
    {
        dim3 g(MCOL/64, (4*HIDD + 63)/64);
        k_gemm_nn<<<g, 256, 0, stream>>>(W_ih, embT, b_ih, b_hh, xgT,
                                         4*HIDD, MCOL, EMBD);
    }

    // 3. persistent cooperative LSTM (all 32 steps, grid-wide sync between steps)
    {
        float* hT_p = hT; const float* xgT_p = xgT;
        const float* Whh_p = W_hh; const float* h0_p = h0;
        const float* c0_p = c0; const int* lens_p = lens;
        void* kargs[] = { (void*)&hT_p, (void*)&xgT_p, (void*)&Whh_p,
                          (void*)&h0_p, (void*)&c0_p, (void*)&lens_p };
        hipLaunchCooperativeKernel((const void*)k_lstm_all, dim3(250), dim3(256),
                                   kargs, 0, stream);
    }

    // 4. g_mlp layer-1 partials (qT = hT, final hidden, transposed)
    k_qp<<<(BATCH*GHID + 255)/256, 256, 0, stream>>>(hT, g1_w, g1_b, qp);
    k_ipjp<<<(BATCH*NOBJ*GHID + 255)/256, 256, 0, stream>>>(conv, g1_w, ip, jp);

    // 5. fused pair kernel -> per-block partial sums
    k_pair<<<BATCH*16, 256, 0, stream>>>(qp, ip, jp, g2_w, g2_b, part);

    // 6. final MLP + log_softmax
    k_final<<<BATCH, 256, 0, stream>>>(part, f1_w, f1_b, f2_w, f2_b, out);
}